// Round 2
// baseline (184.996 us; speedup 1.0000x reference)
//
#include <hip/hip_runtime.h>
#include <math.h>
#include <stdint.h>

#define B_  16
#define N_  512
#define C_  384
#define K_  64
#define NN_ (N_*N_)   // 262144

typedef short bf16x8 __attribute__((ext_vector_type(8)));
typedef float f32x4  __attribute__((ext_vector_type(4)));

// fp32 -> bf16 round-to-nearest-even (inputs finite, no NaN path needed)
__device__ __forceinline__ unsigned short f2bf(float f) {
    union { float f; unsigned u; } v; v.f = f;
    unsigned r = v.u + 0x7FFF + ((v.u >> 16) & 1);
    return (unsigned short)(r >> 16);
}
__device__ __forceinline__ unsigned pack2(float a, float b) {
    return ((unsigned)f2bf(b) << 16) | f2bf(a);
}

// async 16-B global -> LDS (lane-contiguous LDS dest required)
__device__ __forceinline__ void gl_lds16(const void* g, void* l) {
    __builtin_amdgcn_global_load_lds(
        (const __attribute__((address_space(1))) unsigned*)g,
        (__attribute__((address_space(3))) unsigned*)l, 16, 0, 0);
}

__device__ __forceinline__ void fma4(float4& c, float s, const float4& v) {
    c.x = fmaf(s, v.x, c.x);
    c.y = fmaf(s, v.y, c.y);
    c.z = fmaf(s, v.z, c.z);
    c.w = fmaf(s, v.w, c.w);
}

// ---------------------------------------------------------------------------
// 1) partial sums part[b][s][c] = sum over 16 rows + emit x as bf16.
//    Fused: the LAST block of each batch (agent-scope acq/rel counter)
//    computes attn[b,:] = softmax_k(cosine(q, centers[:,k])) in-place.
//    Removes the standalone 16-block attn dispatch from the critical path.
// ---------------------------------------------------------------------------
__global__ __launch_bounds__(384) void mean_attn_kernel(const float* __restrict__ x,
                                                        float* __restrict__ part,
                                                        unsigned short* __restrict__ xb,
                                                        const float* __restrict__ centers,
                                                        float* __restrict__ attn,
                                                        unsigned* __restrict__ cnt) {
    const int b = blockIdx.y;
    const int s = blockIdx.x;
    const int tid = threadIdx.x;
    {
        const size_t base = ((size_t)(b * N_ + s * 16)) * C_ + tid;
        const float* xp = x + base;
        unsigned short* xo = xb + base;
        float acc = 0.f;
#pragma unroll
        for (int i = 0; i < 16; ++i) {
            float v = xp[(size_t)i * C_];
            acc += v;
            xo[(size_t)i * C_] = f2bf(v);
        }
        part[((size_t)b * 32 + s) * C_ + tid] = acc;
    }

    __syncthreads();                       // all waves drain their stores (vmcnt)
    __shared__ bool amLast;
    if (tid == 0) {
        unsigned prev = __hip_atomic_fetch_add(&cnt[b], 1u,
                                               __ATOMIC_ACQ_REL,
                                               __HIP_MEMORY_SCOPE_AGENT);
        amLast = (prev == 31u);
    }
    __syncthreads();
    if (!amLast) return;

    // ---- attn tail: only the 32nd-finishing block of batch b runs this ----
    __threadfence();                       // acquire: see all 32 part slices
    __shared__ float q_lds[C_];
    __shared__ float red[6];
    __shared__ float lg[K_];

    const float* pb = part + (size_t)b * 32 * C_ + tid;
    float qs = 0.f;
#pragma unroll
    for (int i = 0; i < 32; ++i) qs += pb[(size_t)i * C_];
    q_lds[tid] = qs;
    float p2 = qs * qs;
#pragma unroll
    for (int off = 32; off > 0; off >>= 1) p2 += __shfl_xor(p2, off);
    if ((tid & 63) == 0) red[tid >> 6] = p2;
    __syncthreads();

    if (tid < 256) {
        const int k = tid >> 2;
        const int g = tid & 3;
        float dot = 0.f, cn2 = 0.f;
        for (int c = g; c < C_; c += 4) {
            float sv = centers[c * K_ + k];
            float qc = q_lds[c];
            dot = fmaf(qc, sv, dot);
            cn2 = fmaf(sv, sv, cn2);
        }
        dot += __shfl_xor(dot, 1); dot += __shfl_xor(dot, 2);
        cn2 += __shfl_xor(cn2, 1); cn2 += __shfl_xor(cn2, 2);
        if (g == 0) {
            const float qn2 = red[0] + red[1] + red[2] + red[3] + red[4] + red[5];
            const float qnorm = fmaxf(sqrtf(qn2), 1e-12f);
            lg[k] = dot / (qnorm * fmaxf(sqrtf(cn2), 1e-12f));
        }
    }
    __syncthreads();

    if (tid < 64) {
        const float logit = lg[tid];
        float m = logit;
#pragma unroll
        for (int off = 32; off > 0; off >>= 1) m = fmaxf(m, __shfl_xor(m, off));
        const float e = expf(logit - m);
        float ssum = e;
#pragma unroll
        for (int off = 32; off > 0; off >>= 1) ssum += __shfl_xor(ssum, off);
        attn[b * K_ + tid] = e / ssum;
    }
}

// ---------------------------------------------------------------------------
// 2+3 fused) blocks [0,256):  tm[b,:,:] = sum_k attn[b,k]*tran[k]  -> bf16
//            blocks [256,1024): xw = x @ W^T (bf16 MFMA) -> xwT[b][c][m]
//    tm is HBM-bound, xw is MFMA-bound -> co-scheduling overlaps the pipes.
//    tm k-loop: explicit 8-deep register prefetch (~1024 FMA-cycles of
//    latency cover >= ~900-cycle HBM latency).
// ---------------------------------------------------------------------------
__global__ __launch_bounds__(256) void tmxw_kernel(const float* __restrict__ tran,
                                                   const float* __restrict__ attn,
                                                   unsigned short* __restrict__ tmb,
                                                   const unsigned short* __restrict__ Xb,
                                                   const float* __restrict__ Wf,
                                                   unsigned short* __restrict__ xwT) {
    __shared__ unsigned short As[64 * 64];
    __shared__ unsigned short Bs[64 * 64];
    __shared__ float T[4][32 * 35];

    const int tid = threadIdx.x;

    if (blockIdx.x < 256) {
        // ------------------- tm path -------------------
        float* a_s = (float*)As;   // [k][b], 1024 floats
        for (int i = tid; i < K_ * B_; i += 256)
            a_s[i] = attn[(i & 15) * K_ + (i >> 4)];
        __syncthreads();

        const size_t j = ((size_t)blockIdx.x * 256 + tid) * 4;
        const float* tp = tran + j;
        float4 acc[B_];
#pragma unroll
        for (int b = 0; b < B_; ++b) acc[b] = make_float4(0.f, 0.f, 0.f, 0.f);

        float4 t[8];
#pragma unroll
        for (int i = 0; i < 8; ++i) t[i] = *(const float4*)(tp + (size_t)i * NN_);

        for (int k = 0; k < K_; k += 8) {
            float4 n[8];
            if (k < K_ - 8) {
#pragma unroll
                for (int i = 0; i < 8; ++i)
                    n[i] = *(const float4*)(tp + (size_t)(k + 8 + i) * NN_);
            }
#pragma unroll
            for (int kk = 0; kk < 8; ++kk) {
                const float4* wp = (const float4*)(a_s + (k + kk) * 16);
                const float4 w0 = wp[0], w1 = wp[1], w2 = wp[2], w3 = wp[3];
                const float4 tv = t[kk];
                fma4(acc[0],  w0.x, tv); fma4(acc[1],  w0.y, tv);
                fma4(acc[2],  w0.z, tv); fma4(acc[3],  w0.w, tv);
                fma4(acc[4],  w1.x, tv); fma4(acc[5],  w1.y, tv);
                fma4(acc[6],  w1.z, tv); fma4(acc[7],  w1.w, tv);
                fma4(acc[8],  w2.x, tv); fma4(acc[9],  w2.y, tv);
                fma4(acc[10], w2.z, tv); fma4(acc[11], w2.w, tv);
                fma4(acc[12], w3.x, tv); fma4(acc[13], w3.y, tv);
                fma4(acc[14], w3.z, tv); fma4(acc[15], w3.w, tv);
            }
            if (k < K_ - 8) {
#pragma unroll
                for (int i = 0; i < 8; ++i) t[i] = n[i];
            }
        }
#pragma unroll
        for (int b = 0; b < B_; ++b)
            *(uint2*)(tmb + (size_t)b * NN_ + j) =
                make_uint2(pack2(acc[b].x, acc[b].y), pack2(acc[b].z, acc[b].w));
        return;
    }

    // ------------------- xw path -------------------
    const int bid  = blockIdx.x - 256;      // [0,768)
    const int row0 = (bid & 127) * 64;
    const int col0 = (bid >> 7) * 64;
    const int lane = tid & 63;
    const int w    = tid >> 6;
    const int wm   = w & 1, wn = w >> 1;
    const int quad = lane >> 4, l15 = lane & 15;

    const int sm = tid >> 3;
    const int sc = tid & 7;

    f32x4 acc[2][2] = {};

    for (int k0 = 0; k0 < C_; k0 += 64) {
        float4 wv[2][2];
#pragma unroll
        for (int p = 0; p < 2; ++p) {
            const int m  = p * 32 + sm;
            const int gc = sc ^ (m & 7);
            const float* src = Wf + (size_t)(col0 + m) * C_ + k0 + gc * 8;
            wv[p][0] = *(const float4*)(src);
            wv[p][1] = *(const float4*)(src + 4);
        }
        __syncthreads();
#pragma unroll
        for (int p = 0; p < 2; ++p) {
            const int m  = p * 32 + sm;
            const int gc = sc ^ (m & 7);
            gl_lds16(Xb + (size_t)(row0 + m) * C_ + k0 + gc * 8,
                     As + (p * 256 + tid) * 8);
            *(uint4*)(Bs + (p * 256 + tid) * 8) =
                make_uint4(pack2(wv[p][0].x, wv[p][0].y),
                           pack2(wv[p][0].z, wv[p][0].w),
                           pack2(wv[p][1].x, wv[p][1].y),
                           pack2(wv[p][1].z, wv[p][1].w));
        }
        __syncthreads();
#pragma unroll
        for (int kk = 0; kk < 2; ++kk) {
            bf16x8 afr[2], bfr[2];
#pragma unroll
            for (int mt = 0; mt < 2; ++mt) {
                const int mr = wm * 32 + mt * 16 + l15;
                const int kc = (kk * 4 + quad) ^ (mr & 7);
                afr[mt] = *(const bf16x8*)(As + mr * 64 + kc * 8);
            }
#pragma unroll
            for (int nt = 0; nt < 2; ++nt) {
                const int nr = wn * 32 + nt * 16 + l15;
                const int kc = (kk * 4 + quad) ^ (nr & 7);
                bfr[nt] = *(const bf16x8*)(Bs + nr * 64 + kc * 8);
            }
#pragma unroll
            for (int mt = 0; mt < 2; ++mt)
#pragma unroll
                for (int nt = 0; nt < 2; ++nt)
                    acc[mt][nt] = __builtin_amdgcn_mfma_f32_16x16x32_bf16(
                        afr[mt], bfr[nt], acc[mt][nt], 0, 0, 0);
        }
    }

#pragma unroll
    for (int mt = 0; mt < 2; ++mt)
#pragma unroll
        for (int nt = 0; nt < 2; ++nt)
#pragma unroll
            for (int r = 0; r < 4; ++r)
                T[w][(mt * 16 + quad * 4 + r) * 35 + nt * 16 + l15] = acc[mt][nt][r];
    __syncthreads();

    const int rw = row0 + wm * 32;
    const int b  = rw >> 9;
    const int m0 = rw & 511;
    const int c0 = col0 + wn * 32;
    unsigned short* dst = xwT + (size_t)b * C_ * N_;
#pragma unroll
    for (int i = 0; i < 8; ++i) {
        const int cl = i * 4 + quad;
        const int ml = l15 * 2;
        const float v0 = T[w][(ml + 0) * 35 + cl];
        const float v1 = T[w][(ml + 1) * 35 + cl];
        *(unsigned*)(dst + (size_t)(c0 + cl) * N_ + m0 + ml) = pack2(v0, v1);
    }
}

// ---------------------------------------------------------------------------
// 4) out[b,n,c] = sum_m tm[b,n,m] * xw[b,m,c] + bias[c]  (bf16 MFMA, fp32 out)
// ---------------------------------------------------------------------------
__global__ __launch_bounds__(256) void out_mfma(const unsigned short* __restrict__ Ab,
                                                const unsigned short* __restrict__ Bt,
                                                const float* __restrict__ bias,
                                                float* __restrict__ out) {
    __shared__ unsigned short As[64 * 64];
    __shared__ unsigned short Bs[64 * 64];

    const int tid  = threadIdx.x;
    const int b    = blockIdx.z;
    const int row0 = blockIdx.x * 64;
    const int col0 = blockIdx.y * 64;
    const int lane = tid & 63;
    const int w    = tid >> 6;
    const int wm   = w & 1, wn = w >> 1;
    const int quad = lane >> 4, l15 = lane & 15;

    const unsigned short* Abase = Ab + (size_t)b * N_ * N_;
    const unsigned short* Bbase = Bt + (size_t)b * C_ * N_;

    const int sm = tid >> 3;
    const int sc = tid & 7;

    f32x4 acc[2][2] = {};

    for (int k0 = 0; k0 < N_; k0 += 64) {
        __syncthreads();
#pragma unroll
        for (int p = 0; p < 2; ++p) {
            const int m  = p * 32 + sm;
            const int gc = sc ^ (m & 7);
            gl_lds16(Abase + (size_t)(row0 + m) * N_ + k0 + gc * 8,
                     As + (p * 256 + tid) * 8);
            gl_lds16(Bbase + (size_t)(col0 + m) * N_ + k0 + gc * 8,
                     Bs + (p * 256 + tid) * 8);
        }
        __syncthreads();
#pragma unroll
        for (int kk = 0; kk < 2; ++kk) {
            bf16x8 afr[2], bfr[2];
#pragma unroll
            for (int mt = 0; mt < 2; ++mt) {
                const int mr = wm * 32 + mt * 16 + l15;
                const int kc = (kk * 4 + quad) ^ (mr & 7);
                afr[mt] = *(const bf16x8*)(As + mr * 64 + kc * 8);
            }
#pragma unroll
            for (int nt = 0; nt < 2; ++nt) {
                const int nr = wn * 32 + nt * 16 + l15;
                const int kc = (kk * 4 + quad) ^ (nr & 7);
                bfr[nt] = *(const bf16x8*)(Bs + nr * 64 + kc * 8);
            }
#pragma unroll
            for (int mt = 0; mt < 2; ++mt)
#pragma unroll
                for (int nt = 0; nt < 2; ++nt)
                    acc[mt][nt] = __builtin_amdgcn_mfma_f32_16x16x32_bf16(
                        afr[mt], bfr[nt], acc[mt][nt], 0, 0, 0);
        }
    }

#pragma unroll
    for (int nt = 0; nt < 2; ++nt) {
        const int c  = col0 + wn * 32 + nt * 16 + l15;
        const float bv = bias[c];
#pragma unroll
        for (int mt = 0; mt < 2; ++mt) {
            const int rbase = row0 + wm * 32 + mt * 16 + quad * 4;
#pragma unroll
            for (int r = 0; r < 4; ++r)
                out[((size_t)(b * N_ + rbase + r)) * C_ + c] = acc[mt][nt][r] + bv;
        }
    }
}

// ---------------------------------------------------------------------------
// launch — 3 dispatches (+ tiny counter memset)
// ---------------------------------------------------------------------------
extern "C" void kernel_launch(void* const* d_in, const int* in_sizes, int n_in,
                              void* d_out, int out_size, void* d_ws, size_t ws_size,
                              hipStream_t stream) {
    const float* x       = (const float*)d_in[0];   // [16,512,384]
    const float* centers = (const float*)d_in[1];   // [384,64]
    const float* tran    = (const float*)d_in[2];   // [64,512,512]
    const float* proj_w  = (const float*)d_in[3];   // [384,384]
    const float* proj_b  = (const float*)d_in[4];   // [384]
    float* out = (float*)d_out;                     // [16,512,384]

    float* ws   = (float*)d_ws;
    float* part = ws;                                    // 16*32*384 floats
    float* attn = ws + 196608;                           // 1024 floats
    unsigned short* tmb = (unsigned short*)(ws + 197632);        // 16*512*512 bf16
    unsigned short* xwT = tmb + (size_t)B_ * N_ * N_;            // 16*384*512 bf16
    unsigned short* xb  = xwT + (size_t)B_ * C_ * N_;            // 16*512*384 bf16
    unsigned* cnt = (unsigned*)(xb + (size_t)B_ * N_ * C_);      // 16 counters

    hipMemsetAsync(cnt, 0, B_ * sizeof(unsigned), stream);
    mean_attn_kernel<<<dim3(32, 16), 384, 0, stream>>>(x, part, xb, centers, attn, cnt);
    tmxw_kernel<<<1024, 256, 0, stream>>>(tran, attn, tmb, xb, proj_w, xwT);
    out_mfma<<<dim3(8, 6, 16), 256, 0, stream>>>(tmb, xwT, proj_b, out);
}

// Round 3
// 161.931 us; speedup vs baseline: 1.1424x; 1.1424x over previous
//
#include <hip/hip_runtime.h>
#include <math.h>
#include <stdint.h>

#define B_  16
#define N_  512
#define C_  384
#define K_  64
#define NN_ (N_*N_)   // 262144

typedef short bf16x8 __attribute__((ext_vector_type(8)));
typedef float f32x4  __attribute__((ext_vector_type(4)));

// fp32 -> bf16 round-to-nearest-even (inputs finite, no NaN path needed)
__device__ __forceinline__ unsigned short f2bf(float f) {
    union { float f; unsigned u; } v; v.f = f;
    unsigned r = v.u + 0x7FFF + ((v.u >> 16) & 1);
    return (unsigned short)(r >> 16);
}
__device__ __forceinline__ unsigned pack2(float a, float b) {
    return ((unsigned)f2bf(b) << 16) | f2bf(a);
}

// async 16-B global -> LDS (lane-contiguous LDS dest required)
__device__ __forceinline__ void gl_lds16(const void* g, void* l) {
    __builtin_amdgcn_global_load_lds(
        (const __attribute__((address_space(1))) unsigned*)g,
        (__attribute__((address_space(3))) unsigned*)l, 16, 0, 0);
}

__device__ __forceinline__ void fma4(float4& c, float s, const float4& v) {
    c.x = fmaf(s, v.x, c.x);
    c.y = fmaf(s, v.y, c.y);
    c.z = fmaf(s, v.z, c.z);
    c.w = fmaf(s, v.w, c.w);
}

// ---------------------------------------------------------------------------
// 1) partial sums part[b][s][c] = sum over 16 rows + emit x as bf16
// ---------------------------------------------------------------------------
__global__ __launch_bounds__(384) void mean_kernel(const float* __restrict__ x,
                                                   float* __restrict__ part,
                                                   unsigned short* __restrict__ xb) {
    const int b = blockIdx.y;
    const int s = blockIdx.x;
    const int c = threadIdx.x;
    const size_t base = ((size_t)(b * N_ + s * 16)) * C_ + c;
    const float* xp = x + base;
    unsigned short* xo = xb + base;
    float acc = 0.f;
#pragma unroll
    for (int i = 0; i < 16; ++i) {
        float v = xp[(size_t)i * C_];
        acc += v;
        xo[(size_t)i * C_] = f2bf(v);
    }
    part[((size_t)b * 32 + s) * C_ + c] = acc;
}

// ---------------------------------------------------------------------------
// 2) attn + xw co-scheduled by blockIdx (independent work, no atomics):
//    blocks [0,16):   attn[b,k] = softmax_k(cosine(q, centers[:,k]))
//    blocks [16,784): xw = x @ W^T (bf16 MFMA) -> xwT[b][c][m]
//    attn is a 96-wave latency bubble -> hidden under 768 MFMA blocks.
// ---------------------------------------------------------------------------
__global__ __launch_bounds__(384) void attnxw_kernel(const float* __restrict__ part,
                                                     const float* __restrict__ centers,
                                                     float* __restrict__ attn,
                                                     const unsigned short* __restrict__ Xb,
                                                     const float* __restrict__ Wf,
                                                     unsigned short* __restrict__ xwT) {
    __shared__ __attribute__((aligned(16))) unsigned short As[64 * 64];
    __shared__ __attribute__((aligned(16))) unsigned short Bs[64 * 64];
    __shared__ float T[4][32 * 35];

    const int tid = threadIdx.x;

    if (blockIdx.x < 16) {
        // ------------------- attn path (16 blocks) -------------------
        float* q_lds = (float*)As;            // 384 floats
        float* red   = (float*)As + 512;      // 6 floats
        float* lg    = (float*)Bs;            // 64 floats
        const int b = blockIdx.x;

        const float* pb = part + (size_t)b * 32 * C_ + tid;
        float s = 0.f;
#pragma unroll
        for (int i = 0; i < 32; ++i) s += pb[(size_t)i * C_];
        q_lds[tid] = s;
        float p2 = s * s;
#pragma unroll
        for (int off = 32; off > 0; off >>= 1) p2 += __shfl_xor(p2, off);
        if ((tid & 63) == 0) red[tid >> 6] = p2;
        __syncthreads();

        if (tid < 256) {
            const int k = tid >> 2;
            const int g = tid & 3;
            float dot = 0.f, cn2 = 0.f;
            for (int c = g; c < C_; c += 4) {
                float sv = centers[c * K_ + k];
                float qc = q_lds[c];
                dot = fmaf(qc, sv, dot);
                cn2 = fmaf(sv, sv, cn2);
            }
            dot += __shfl_xor(dot, 1); dot += __shfl_xor(dot, 2);
            cn2 += __shfl_xor(cn2, 1); cn2 += __shfl_xor(cn2, 2);
            if (g == 0) {
                const float qn2 = red[0] + red[1] + red[2] + red[3] + red[4] + red[5];
                const float qnorm = fmaxf(sqrtf(qn2), 1e-12f);
                lg[k] = dot / (qnorm * fmaxf(sqrtf(cn2), 1e-12f));
            }
        }
        __syncthreads();

        if (tid < 64) {
            const float logit = lg[tid];
            float m = logit;
#pragma unroll
            for (int off = 32; off > 0; off >>= 1) m = fmaxf(m, __shfl_xor(m, off));
            const float e = expf(logit - m);
            float ssum = e;
#pragma unroll
            for (int off = 32; off > 0; off >>= 1) ssum += __shfl_xor(ssum, off);
            attn[b * K_ + tid] = e / ssum;
        }
        return;
    }

    // ------------------- xw path (768 blocks, 4 live waves) -------------------
    if (tid >= 256) return;                 // waves 4,5 exit before any barrier

    const int bid  = blockIdx.x - 16;       // [0,768)
    const int row0 = (bid & 127) * 64;
    const int col0 = (bid >> 7) * 64;
    const int lane = tid & 63;
    const int w    = tid >> 6;
    const int wm   = w & 1, wn = w >> 1;
    const int quad = lane >> 4, l15 = lane & 15;

    const int sm = tid >> 3;
    const int sc = tid & 7;

    f32x4 acc[2][2] = {};

    for (int k0 = 0; k0 < C_; k0 += 64) {
        float4 wv[2][2];
#pragma unroll
        for (int p = 0; p < 2; ++p) {
            const int m  = p * 32 + sm;
            const int gc = sc ^ (m & 7);
            const float* src = Wf + (size_t)(col0 + m) * C_ + k0 + gc * 8;
            wv[p][0] = *(const float4*)(src);
            wv[p][1] = *(const float4*)(src + 4);
        }
        __syncthreads();
#pragma unroll
        for (int p = 0; p < 2; ++p) {
            const int m  = p * 32 + sm;
            const int gc = sc ^ (m & 7);
            gl_lds16(Xb + (size_t)(row0 + m) * C_ + k0 + gc * 8,
                     As + (p * 256 + tid) * 8);
            *(uint4*)(Bs + (p * 256 + tid) * 8) =
                make_uint4(pack2(wv[p][0].x, wv[p][0].y),
                           pack2(wv[p][0].z, wv[p][0].w),
                           pack2(wv[p][1].x, wv[p][1].y),
                           pack2(wv[p][1].z, wv[p][1].w));
        }
        __syncthreads();
#pragma unroll
        for (int kk = 0; kk < 2; ++kk) {
            bf16x8 afr[2], bfr[2];
#pragma unroll
            for (int mt = 0; mt < 2; ++mt) {
                const int mr = wm * 32 + mt * 16 + l15;
                const int kc = (kk * 4 + quad) ^ (mr & 7);
                afr[mt] = *(const bf16x8*)(As + mr * 64 + kc * 8);
            }
#pragma unroll
            for (int nt = 0; nt < 2; ++nt) {
                const int nr = wn * 32 + nt * 16 + l15;
                const int kc = (kk * 4 + quad) ^ (nr & 7);
                bfr[nt] = *(const bf16x8*)(Bs + nr * 64 + kc * 8);
            }
#pragma unroll
            for (int mt = 0; mt < 2; ++mt)
#pragma unroll
                for (int nt = 0; nt < 2; ++nt)
                    acc[mt][nt] = __builtin_amdgcn_mfma_f32_16x16x32_bf16(
                        afr[mt], bfr[nt], acc[mt][nt], 0, 0, 0);
        }
    }

#pragma unroll
    for (int mt = 0; mt < 2; ++mt)
#pragma unroll
        for (int nt = 0; nt < 2; ++nt)
#pragma unroll
            for (int r = 0; r < 4; ++r)
                T[w][(mt * 16 + quad * 4 + r) * 35 + nt * 16 + l15] = acc[mt][nt][r];
    __syncthreads();

    const int rw = row0 + wm * 32;
    const int b  = rw >> 9;
    const int m0 = rw & 511;
    const int c0 = col0 + wn * 32;
    unsigned short* dst = xwT + (size_t)b * C_ * N_;
#pragma unroll
    for (int i = 0; i < 8; ++i) {
        const int cl = i * 4 + quad;
        const int ml = l15 * 2;
        const float v0 = T[w][(ml + 0) * 35 + cl];
        const float v1 = T[w][(ml + 1) * 35 + cl];
        *(unsigned*)(dst + (size_t)(c0 + cl) * N_ + m0 + ml) = pack2(v0, v1);
    }
}

// ---------------------------------------------------------------------------
// 3) tm[b,:,:] = sum_k attn[b,k]*tran[k] -> bf16  (standalone HBM stream,
//    8-deep register prefetch ≈ 1024 FMA-cycles of latency cover)
// ---------------------------------------------------------------------------
__global__ __launch_bounds__(256) void tm_kernel(const float* __restrict__ tran,
                                                 const float* __restrict__ attn,
                                                 unsigned short* __restrict__ tmb) {
    __shared__ float a_s[K_ * B_];   // [k][b], 1024 floats
    const int tid = threadIdx.x;

    for (int i = tid; i < K_ * B_; i += 256)
        a_s[i] = attn[(i & 15) * K_ + (i >> 4)];
    __syncthreads();

    const size_t j = ((size_t)blockIdx.x * 256 + tid) * 4;
    const float* tp = tran + j;
    float4 acc[B_];
#pragma unroll
    for (int b = 0; b < B_; ++b) acc[b] = make_float4(0.f, 0.f, 0.f, 0.f);

    float4 t[8];
#pragma unroll
    for (int i = 0; i < 8; ++i) t[i] = *(const float4*)(tp + (size_t)i * NN_);

    for (int k = 0; k < K_; k += 8) {
        float4 n[8];
        if (k < K_ - 8) {
#pragma unroll
            for (int i = 0; i < 8; ++i)
                n[i] = *(const float4*)(tp + (size_t)(k + 8 + i) * NN_);
        }
#pragma unroll
        for (int kk = 0; kk < 8; ++kk) {
            const float4* wp = (const float4*)(a_s + (k + kk) * 16);
            const float4 w0 = wp[0], w1 = wp[1], w2 = wp[2], w3 = wp[3];
            const float4 tv = t[kk];
            fma4(acc[0],  w0.x, tv); fma4(acc[1],  w0.y, tv);
            fma4(acc[2],  w0.z, tv); fma4(acc[3],  w0.w, tv);
            fma4(acc[4],  w1.x, tv); fma4(acc[5],  w1.y, tv);
            fma4(acc[6],  w1.z, tv); fma4(acc[7],  w1.w, tv);
            fma4(acc[8],  w2.x, tv); fma4(acc[9],  w2.y, tv);
            fma4(acc[10], w2.z, tv); fma4(acc[11], w2.w, tv);
            fma4(acc[12], w3.x, tv); fma4(acc[13], w3.y, tv);
            fma4(acc[14], w3.z, tv); fma4(acc[15], w3.w, tv);
        }
        if (k < K_ - 8) {
#pragma unroll
            for (int i = 0; i < 8; ++i) t[i] = n[i];
        }
    }
#pragma unroll
    for (int b = 0; b < B_; ++b)
        *(uint2*)(tmb + (size_t)b * NN_ + j) =
            make_uint2(pack2(acc[b].x, acc[b].y), pack2(acc[b].z, acc[b].w));
}

// ---------------------------------------------------------------------------
// 4) out[b,n,c] = sum_m tm[b,n,m] * xw[b,m,c] + bias[c]  (bf16 MFMA, fp32 out)
// ---------------------------------------------------------------------------
__global__ __launch_bounds__(256) void out_mfma(const unsigned short* __restrict__ Ab,
                                                const unsigned short* __restrict__ Bt,
                                                const float* __restrict__ bias,
                                                float* __restrict__ out) {
    __shared__ unsigned short As[64 * 64];
    __shared__ unsigned short Bs[64 * 64];

    const int tid  = threadIdx.x;
    const int b    = blockIdx.z;
    const int row0 = blockIdx.x * 64;
    const int col0 = blockIdx.y * 64;
    const int lane = tid & 63;
    const int w    = tid >> 6;
    const int wm   = w & 1, wn = w >> 1;
    const int quad = lane >> 4, l15 = lane & 15;

    const unsigned short* Abase = Ab + (size_t)b * N_ * N_;
    const unsigned short* Bbase = Bt + (size_t)b * C_ * N_;

    const int sm = tid >> 3;
    const int sc = tid & 7;

    f32x4 acc[2][2] = {};

    for (int k0 = 0; k0 < N_; k0 += 64) {
        __syncthreads();
#pragma unroll
        for (int p = 0; p < 2; ++p) {
            const int m  = p * 32 + sm;
            const int gc = sc ^ (m & 7);
            gl_lds16(Abase + (size_t)(row0 + m) * N_ + k0 + gc * 8,
                     As + (p * 256 + tid) * 8);
            gl_lds16(Bbase + (size_t)(col0 + m) * N_ + k0 + gc * 8,
                     Bs + (p * 256 + tid) * 8);
        }
        __syncthreads();
#pragma unroll
        for (int kk = 0; kk < 2; ++kk) {
            bf16x8 afr[2], bfr[2];
#pragma unroll
            for (int mt = 0; mt < 2; ++mt) {
                const int mr = wm * 32 + mt * 16 + l15;
                const int kc = (kk * 4 + quad) ^ (mr & 7);
                afr[mt] = *(const bf16x8*)(As + mr * 64 + kc * 8);
            }
#pragma unroll
            for (int nt = 0; nt < 2; ++nt) {
                const int nr = wn * 32 + nt * 16 + l15;
                const int kc = (kk * 4 + quad) ^ (nr & 7);
                bfr[nt] = *(const bf16x8*)(Bs + nr * 64 + kc * 8);
            }
#pragma unroll
            for (int mt = 0; mt < 2; ++mt)
#pragma unroll
                for (int nt = 0; nt < 2; ++nt)
                    acc[mt][nt] = __builtin_amdgcn_mfma_f32_16x16x32_bf16(
                        afr[mt], bfr[nt], acc[mt][nt], 0, 0, 0);
        }
    }

#pragma unroll
    for (int nt = 0; nt < 2; ++nt) {
        const int c  = col0 + wn * 32 + nt * 16 + l15;
        const float bv = bias[c];
#pragma unroll
        for (int mt = 0; mt < 2; ++mt) {
            const int rbase = row0 + wm * 32 + mt * 16 + quad * 4;
#pragma unroll
            for (int r = 0; r < 4; ++r)
                out[((size_t)(b * N_ + rbase + r)) * C_ + c] = acc[mt][nt][r] + bv;
        }
    }
}

// ---------------------------------------------------------------------------
// launch — 4 dispatches, no atomics
// ---------------------------------------------------------------------------
extern "C" void kernel_launch(void* const* d_in, const int* in_sizes, int n_in,
                              void* d_out, int out_size, void* d_ws, size_t ws_size,
                              hipStream_t stream) {
    const float* x       = (const float*)d_in[0];   // [16,512,384]
    const float* centers = (const float*)d_in[1];   // [384,64]
    const float* tran    = (const float*)d_in[2];   // [64,512,512]
    const float* proj_w  = (const float*)d_in[3];   // [384,384]
    const float* proj_b  = (const float*)d_in[4];   // [384]
    float* out = (float*)d_out;                     // [16,512,384]

    float* ws   = (float*)d_ws;
    float* part = ws;                                    // 16*32*384 floats
    float* attn = ws + 196608;                           // 1024 floats
    unsigned short* tmb = (unsigned short*)(ws + 197632);        // 16*512*512 bf16
    unsigned short* xwT = tmb + (size_t)B_ * N_ * N_;            // 16*384*512 bf16
    unsigned short* xb  = xwT + (size_t)B_ * C_ * N_;            // 16*512*384 bf16

    mean_kernel<<<dim3(32, 16), 384, 0, stream>>>(x, part, xb);
    attnxw_kernel<<<784, 384, 0, stream>>>(part, centers, attn, xb, proj_w, xwT);
    tm_kernel<<<256, 256, 0, stream>>>(tran, attn, tmb);
    out_mfma<<<dim3(8, 6, 16), 256, 0, stream>>>(tmb, xwT, proj_b, out);
}

// Round 4
// 137.137 us; speedup vs baseline: 1.3490x; 1.1808x over previous
//
#include <hip/hip_runtime.h>
#include <math.h>
#include <stdint.h>

#define B_  16
#define N_  512
#define C_  384
#define K_  64
#define NN_ (N_*N_)   // 262144

typedef short bf16x8 __attribute__((ext_vector_type(8)));
typedef float f32x4  __attribute__((ext_vector_type(4)));

// fp32 -> bf16 round-to-nearest-even (inputs finite, no NaN path needed)
__device__ __forceinline__ unsigned short f2bf(float f) {
    union { float f; unsigned u; } v; v.f = f;
    unsigned r = v.u + 0x7FFF + ((v.u >> 16) & 1);
    return (unsigned short)(r >> 16);
}
__device__ __forceinline__ unsigned pack2(float a, float b) {
    return ((unsigned)f2bf(b) << 16) | f2bf(a);
}

// async 16-B global -> LDS (lane-contiguous LDS dest required)
__device__ __forceinline__ void gl_lds16(const void* g, void* l) {
    __builtin_amdgcn_global_load_lds(
        (const __attribute__((address_space(1))) unsigned*)g,
        (__attribute__((address_space(3))) unsigned*)l, 16, 0, 0);
}

__device__ __forceinline__ void fma4(float4& c, float s, const float4& v) {
    c.x = fmaf(s, v.x, c.x);
    c.y = fmaf(s, v.y, c.y);
    c.z = fmaf(s, v.z, c.z);
    c.w = fmaf(s, v.w, c.w);
}

// ---------------------------------------------------------------------------
// 1) partial sums part[b][s][c] = sum over 16 rows + emit x as bf16
// ---------------------------------------------------------------------------
__global__ __launch_bounds__(384) void mean_kernel(const float* __restrict__ x,
                                                   float* __restrict__ part,
                                                   unsigned short* __restrict__ xb) {
    const int b = blockIdx.y;
    const int s = blockIdx.x;
    const int c = threadIdx.x;
    const size_t base = ((size_t)(b * N_ + s * 16)) * C_ + c;
    const float* xp = x + base;
    unsigned short* xo = xb + base;
    float acc = 0.f;
#pragma unroll
    for (int i = 0; i < 16; ++i) {
        float v = xp[(size_t)i * C_];
        acc += v;
        xo[(size_t)i * C_] = f2bf(v);
    }
    part[((size_t)b * 32 + s) * C_ + c] = acc;
}

// ---------------------------------------------------------------------------
// 2) attn + xw co-scheduled by blockIdx (independent work, no atomics):
//    blocks [0,16):   attn[b,k] = softmax_k(cosine(q, centers[:,k]))
//      dot phase: wave w owns c-chunk [64w,64w+64), lane = k. Fully-unrolled
//      64-iter loop, coalesced 256-B loads, deep ILP (the r3 version had a
//      runtime-bound 96-iter loop paying serial load latency -> ~40 us).
//    blocks [16,784): xw = x @ W^T (bf16 MFMA) -> xwT[b][c][m]
// ---------------------------------------------------------------------------
__global__ __launch_bounds__(384) void attnxw_kernel(const float* __restrict__ part,
                                                     const float* __restrict__ centers,
                                                     float* __restrict__ attn,
                                                     const unsigned short* __restrict__ Xb,
                                                     const float* __restrict__ Wf,
                                                     unsigned short* __restrict__ xwT) {
    __shared__ __attribute__((aligned(16))) unsigned short As[64 * 64];
    __shared__ __attribute__((aligned(16))) unsigned short Bs[64 * 64];
    __shared__ float T[4][32 * 35];

    const int tid = threadIdx.x;

    if (blockIdx.x < 16) {
        // ------------------- attn path (16 blocks, 6 waves each) -----------
        float* q_lds = (float*)As;            // 384 floats
        float* red   = (float*)As + 512;      // 6 floats
        float* pd    = (float*)As + 1024;     // 384 floats (per-wave dot partials)
        float* pc    = (float*)Bs;            // 384 floats (per-wave cn2 partials)
        float* lg    = (float*)Bs + 512;      // 64 floats
        const int b = blockIdx.x;

        const float* pb = part + (size_t)b * 32 * C_ + tid;
        float s = 0.f;
#pragma unroll
        for (int i = 0; i < 32; ++i) s += pb[(size_t)i * C_];
        q_lds[tid] = s;
        float p2 = s * s;
#pragma unroll
        for (int off = 32; off > 0; off >>= 1) p2 += __shfl_xor(p2, off);
        if ((tid & 63) == 0) red[tid >> 6] = p2;
        __syncthreads();

        {
            const int w    = tid >> 6;        // wave 0..5 -> c-chunk
            const int lane = tid & 63;        // lane = k
            const int c0   = w * 64;
            const float* cp = centers + (size_t)c0 * K_ + lane;
            float dot = 0.f, cn2 = 0.f;
#pragma unroll
            for (int i = 0; i < 64; ++i) {
                const float sv = cp[(size_t)i * K_];
                const float qc = q_lds[c0 + i];
                dot = fmaf(qc, sv, dot);
                cn2 = fmaf(sv, sv, cn2);
            }
            pd[w * 64 + lane] = dot;
            pc[w * 64 + lane] = cn2;
        }
        __syncthreads();

        if (tid < 64) {
            float dot = 0.f, cn2 = 0.f;
#pragma unroll
            for (int w = 0; w < 6; ++w) {
                dot += pd[w * 64 + tid];
                cn2 += pc[w * 64 + tid];
            }
            const float qn2 = red[0] + red[1] + red[2] + red[3] + red[4] + red[5];
            const float qnorm = fmaxf(sqrtf(qn2), 1e-12f);
            const float logit = dot / (qnorm * fmaxf(sqrtf(cn2), 1e-12f));

            float m = logit;
#pragma unroll
            for (int off = 32; off > 0; off >>= 1) m = fmaxf(m, __shfl_xor(m, off));
            const float e = expf(logit - m);
            float ssum = e;
#pragma unroll
            for (int off = 32; off > 0; off >>= 1) ssum += __shfl_xor(ssum, off);
            attn[b * K_ + tid] = e / ssum;
        }
        return;
    }

    // ------------------- xw path (768 blocks, 4 live waves) -------------------
    if (tid >= 256) return;                 // waves 4,5 exit before any barrier

    const int bid  = blockIdx.x - 16;       // [0,768)
    const int row0 = (bid & 127) * 64;
    const int col0 = (bid >> 7) * 64;
    const int lane = tid & 63;
    const int w    = tid >> 6;
    const int wm   = w & 1, wn = w >> 1;
    const int quad = lane >> 4, l15 = lane & 15;

    const int sm = tid >> 3;
    const int sc = tid & 7;

    f32x4 acc[2][2] = {};

    for (int k0 = 0; k0 < C_; k0 += 64) {
        float4 wv[2][2];
#pragma unroll
        for (int p = 0; p < 2; ++p) {
            const int m  = p * 32 + sm;
            const int gc = sc ^ (m & 7);
            const float* src = Wf + (size_t)(col0 + m) * C_ + k0 + gc * 8;
            wv[p][0] = *(const float4*)(src);
            wv[p][1] = *(const float4*)(src + 4);
        }
        __syncthreads();
#pragma unroll
        for (int p = 0; p < 2; ++p) {
            const int m  = p * 32 + sm;
            const int gc = sc ^ (m & 7);
            gl_lds16(Xb + (size_t)(row0 + m) * C_ + k0 + gc * 8,
                     As + (p * 256 + tid) * 8);
            *(uint4*)(Bs + (p * 256 + tid) * 8) =
                make_uint4(pack2(wv[p][0].x, wv[p][0].y),
                           pack2(wv[p][0].z, wv[p][0].w),
                           pack2(wv[p][1].x, wv[p][1].y),
                           pack2(wv[p][1].z, wv[p][1].w));
        }
        __syncthreads();
#pragma unroll
        for (int kk = 0; kk < 2; ++kk) {
            bf16x8 afr[2], bfr[2];
#pragma unroll
            for (int mt = 0; mt < 2; ++mt) {
                const int mr = wm * 32 + mt * 16 + l15;
                const int kc = (kk * 4 + quad) ^ (mr & 7);
                afr[mt] = *(const bf16x8*)(As + mr * 64 + kc * 8);
            }
#pragma unroll
            for (int nt = 0; nt < 2; ++nt) {
                const int nr = wn * 32 + nt * 16 + l15;
                const int kc = (kk * 4 + quad) ^ (nr & 7);
                bfr[nt] = *(const bf16x8*)(Bs + nr * 64 + kc * 8);
            }
#pragma unroll
            for (int mt = 0; mt < 2; ++mt)
#pragma unroll
                for (int nt = 0; nt < 2; ++nt)
                    acc[mt][nt] = __builtin_amdgcn_mfma_f32_16x16x32_bf16(
                        afr[mt], bfr[nt], acc[mt][nt], 0, 0, 0);
        }
    }

#pragma unroll
    for (int mt = 0; mt < 2; ++mt)
#pragma unroll
        for (int nt = 0; nt < 2; ++nt)
#pragma unroll
            for (int r = 0; r < 4; ++r)
                T[w][(mt * 16 + quad * 4 + r) * 35 + nt * 16 + l15] = acc[mt][nt][r];
    __syncthreads();

    const int rw = row0 + wm * 32;
    const int b  = rw >> 9;
    const int m0 = rw & 511;
    const int c0 = col0 + wn * 32;
    unsigned short* dst = xwT + (size_t)b * C_ * N_;
#pragma unroll
    for (int i = 0; i < 8; ++i) {
        const int cl = i * 4 + quad;
        const int ml = l15 * 2;
        const float v0 = T[w][(ml + 0) * 35 + cl];
        const float v1 = T[w][(ml + 1) * 35 + cl];
        *(unsigned*)(dst + (size_t)(c0 + cl) * N_ + m0 + ml) = pack2(v0, v1);
    }
}

// ---------------------------------------------------------------------------
// 3) tm[b,:,:] = sum_k attn[b,k]*tran[k] -> bf16  (standalone HBM stream,
//    8-deep register prefetch ≈ 1024 FMA-cycles of latency cover)
// ---------------------------------------------------------------------------
__global__ __launch_bounds__(256) void tm_kernel(const float* __restrict__ tran,
                                                 const float* __restrict__ attn,
                                                 unsigned short* __restrict__ tmb) {
    __shared__ float a_s[K_ * B_];   // [k][b], 1024 floats
    const int tid = threadIdx.x;

    for (int i = tid; i < K_ * B_; i += 256)
        a_s[i] = attn[(i & 15) * K_ + (i >> 4)];
    __syncthreads();

    const size_t j = ((size_t)blockIdx.x * 256 + tid) * 4;
    const float* tp = tran + j;
    float4 acc[B_];
#pragma unroll
    for (int b = 0; b < B_; ++b) acc[b] = make_float4(0.f, 0.f, 0.f, 0.f);

    float4 t[8];
#pragma unroll
    for (int i = 0; i < 8; ++i) t[i] = *(const float4*)(tp + (size_t)i * NN_);

    for (int k = 0; k < K_; k += 8) {
        float4 n[8];
        if (k < K_ - 8) {
#pragma unroll
            for (int i = 0; i < 8; ++i)
                n[i] = *(const float4*)(tp + (size_t)(k + 8 + i) * NN_);
        }
#pragma unroll
        for (int kk = 0; kk < 8; ++kk) {
            const float4* wp = (const float4*)(a_s + (k + kk) * 16);
            const float4 w0 = wp[0], w1 = wp[1], w2 = wp[2], w3 = wp[3];
            const float4 tv = t[kk];
            fma4(acc[0],  w0.x, tv); fma4(acc[1],  w0.y, tv);
            fma4(acc[2],  w0.z, tv); fma4(acc[3],  w0.w, tv);
            fma4(acc[4],  w1.x, tv); fma4(acc[5],  w1.y, tv);
            fma4(acc[6],  w1.z, tv); fma4(acc[7],  w1.w, tv);
            fma4(acc[8],  w2.x, tv); fma4(acc[9],  w2.y, tv);
            fma4(acc[10], w2.z, tv); fma4(acc[11], w2.w, tv);
            fma4(acc[12], w3.x, tv); fma4(acc[13], w3.y, tv);
            fma4(acc[14], w3.z, tv); fma4(acc[15], w3.w, tv);
        }
        if (k < K_ - 8) {
#pragma unroll
            for (int i = 0; i < 8; ++i) t[i] = n[i];
        }
    }
#pragma unroll
    for (int b = 0; b < B_; ++b)
        *(uint2*)(tmb + (size_t)b * NN_ + j) =
            make_uint2(pack2(acc[b].x, acc[b].y), pack2(acc[b].z, acc[b].w));
}

// ---------------------------------------------------------------------------
// 4) out[b,n,c] = sum_m tm[b,n,m] * xw[b,m,c] + bias[c]  (bf16 MFMA, fp32 out)
// ---------------------------------------------------------------------------
__global__ __launch_bounds__(256) void out_mfma(const unsigned short* __restrict__ Ab,
                                                const unsigned short* __restrict__ Bt,
                                                const float* __restrict__ bias,
                                                float* __restrict__ out) {
    __shared__ unsigned short As[64 * 64];
    __shared__ unsigned short Bs[64 * 64];

    const int tid  = threadIdx.x;
    const int b    = blockIdx.z;
    const int row0 = blockIdx.x * 64;
    const int col0 = blockIdx.y * 64;
    const int lane = tid & 63;
    const int w    = tid >> 6;
    const int wm   = w & 1, wn = w >> 1;
    const int quad = lane >> 4, l15 = lane & 15;

    const unsigned short* Abase = Ab + (size_t)b * N_ * N_;
    const unsigned short* Bbase = Bt + (size_t)b * C_ * N_;

    const int sm = tid >> 3;
    const int sc = tid & 7;

    f32x4 acc[2][2] = {};

    for (int k0 = 0; k0 < N_; k0 += 64) {
        __syncthreads();
#pragma unroll
        for (int p = 0; p < 2; ++p) {
            const int m  = p * 32 + sm;
            const int gc = sc ^ (m & 7);
            gl_lds16(Abase + (size_t)(row0 + m) * N_ + k0 + gc * 8,
                     As + (p * 256 + tid) * 8);
            gl_lds16(Bbase + (size_t)(col0 + m) * N_ + k0 + gc * 8,
                     Bs + (p * 256 + tid) * 8);
        }
        __syncthreads();
#pragma unroll
        for (int kk = 0; kk < 2; ++kk) {
            bf16x8 afr[2], bfr[2];
#pragma unroll
            for (int mt = 0; mt < 2; ++mt) {
                const int mr = wm * 32 + mt * 16 + l15;
                const int kc = (kk * 4 + quad) ^ (mr & 7);
                afr[mt] = *(const bf16x8*)(As + mr * 64 + kc * 8);
            }
#pragma unroll
            for (int nt = 0; nt < 2; ++nt) {
                const int nr = wn * 32 + nt * 16 + l15;
                const int kc = (kk * 4 + quad) ^ (nr & 7);
                bfr[nt] = *(const bf16x8*)(Bs + nr * 64 + kc * 8);
            }
#pragma unroll
            for (int mt = 0; mt < 2; ++mt)
#pragma unroll
                for (int nt = 0; nt < 2; ++nt)
                    acc[mt][nt] = __builtin_amdgcn_mfma_f32_16x16x32_bf16(
                        afr[mt], bfr[nt], acc[mt][nt], 0, 0, 0);
        }
    }

#pragma unroll
    for (int nt = 0; nt < 2; ++nt) {
        const int c  = col0 + wn * 32 + nt * 16 + l15;
        const float bv = bias[c];
#pragma unroll
        for (int mt = 0; mt < 2; ++mt) {
            const int rbase = row0 + wm * 32 + mt * 16 + quad * 4;
#pragma unroll
            for (int r = 0; r < 4; ++r)
                out[((size_t)(b * N_ + rbase + r)) * C_ + c] = acc[mt][nt][r] + bv;
        }
    }
}

// ---------------------------------------------------------------------------
// launch — 4 dispatches, no atomics
// ---------------------------------------------------------------------------
extern "C" void kernel_launch(void* const* d_in, const int* in_sizes, int n_in,
                              void* d_out, int out_size, void* d_ws, size_t ws_size,
                              hipStream_t stream) {
    const float* x       = (const float*)d_in[0];   // [16,512,384]
    const float* centers = (const float*)d_in[1];   // [384,64]
    const float* tran    = (const float*)d_in[2];   // [64,512,512]
    const float* proj_w  = (const float*)d_in[3];   // [384,384]
    const float* proj_b  = (const float*)d_in[4];   // [384]
    float* out = (float*)d_out;                     // [16,512,384]

    float* ws   = (float*)d_ws;
    float* part = ws;                                    // 16*32*384 floats
    float* attn = ws + 196608;                           // 1024 floats
    unsigned short* tmb = (unsigned short*)(ws + 197632);        // 16*512*512 bf16
    unsigned short* xwT = tmb + (size_t)B_ * N_ * N_;            // 16*384*512 bf16
    unsigned short* xb  = xwT + (size_t)B_ * C_ * N_;            // 16*512*384 bf16

    mean_kernel<<<dim3(32, 16), 384, 0, stream>>>(x, part, xb);
    attnxw_kernel<<<784, 384, 0, stream>>>(part, centers, attn, xb, proj_w, xwT);
    tm_kernel<<<256, 256, 0, stream>>>(tran, attn, tmb);
    out_mfma<<<dim3(8, 6, 16), 256, 0, stream>>>(tmb, xwT, proj_b, out);
}